// Round 5
// baseline (1220.452 us; speedup 1.0000x reference)
//
#include <hip/hip_runtime.h>
#include <cmath>

#define D 128
#define HID 64

__device__ __forceinline__ float silu_f(float x) { return x / (1.0f + expf(-x)); }

__device__ __forceinline__ float4 fma4(float a, float4 w, float4 c) {
    c.x = fmaf(a, w.x, c.x); c.y = fmaf(a, w.y, c.y);
    c.z = fmaf(a, w.z, c.z); c.w = fmaf(a, w.w, c.w);
    return c;
}
__device__ __forceinline__ float4 silu4(float4 v) {
    v.x = silu_f(v.x); v.y = silu_f(v.y); v.z = silu_f(v.z); v.w = silu_f(v.w);
    return v;
}
__device__ __forceinline__ float dot4(float4 a, float4 b) {
    return fmaf(a.x, b.x, fmaf(a.y, b.y, fmaf(a.z, b.z, a.w * b.w)));
}

// order-preserving float <-> uint encode for atomicMax on floats
__device__ __forceinline__ unsigned fenc(float f) {
    unsigned u = __float_as_uint(f);
    return (u & 0x80000000u) ? ~u : (u | 0x80000000u);
}
__device__ __forceinline__ float fdec(unsigned e) {
    unsigned u = (e & 0x80000000u) ? (e & 0x7FFFFFFFu) : ~e;
    return __uint_as_float(u);
}

__global__ void k_copy(const float* __restrict__ src, float* __restrict__ dst, int n4) {
    int i = blockIdx.x * blockDim.x + threadIdx.x;
    if (i < n4) reinterpret_cast<float4*>(dst)[i] = reinterpret_cast<const float4*>(src)[i];
}

// ---- protection net: 4 lanes per node, split-K, two 32-unit passes (f32) ----
__global__ __launch_bounds__(256) void k_protect(
    const float* __restrict__ states, const float* __restrict__ caps,
    const float* __restrict__ pw1, const float* __restrict__ pb1,
    const float* __restrict__ pw2, const float* __restrict__ pb2,
    unsigned* __restrict__ mask, unsigned* __restrict__ mlist,
    unsigned* __restrict__ counters, float* __restrict__ outmask, int N) {
    unsigned t = blockIdx.x * 256u + threadIdx.x;
    unsigned n = t >> 2, p = t & 3u;
    if (n >= (unsigned)N) return;
    float bs = (p == 0) ? 1.0f : 0.0f;
    const float4* row = reinterpret_cast<const float4*>(states + (size_t)n * D + p * 32);
    float cap = (p == 3) ? caps[n] : 0.0f;
    float act = pb2[0];

#define PASS(ETA)                                                                        \
    {                                                                                    \
        float4 a0, a1, a2, a3, a4, a5, a6, a7;                                           \
        { const float4* b4 = reinterpret_cast<const float4*>(pb1 + (ETA) * 32);          \
          a0 = b4[0]; a1 = b4[1]; a2 = b4[2]; a3 = b4[3];                                \
          a4 = b4[4]; a5 = b4[5]; a6 = b4[6]; a7 = b4[7];                                \
          a0.x*=bs;a0.y*=bs;a0.z*=bs;a0.w*=bs; a1.x*=bs;a1.y*=bs;a1.z*=bs;a1.w*=bs;      \
          a2.x*=bs;a2.y*=bs;a2.z*=bs;a2.w*=bs; a3.x*=bs;a3.y*=bs;a3.z*=bs;a3.w*=bs;      \
          a4.x*=bs;a4.y*=bs;a4.z*=bs;a4.w*=bs; a5.x*=bs;a5.y*=bs;a5.z*=bs;a5.w*=bs;      \
          a6.x*=bs;a6.y*=bs;a6.z*=bs;a6.w*=bs; a7.x*=bs;a7.y*=bs;a7.z*=bs;a7.w*=bs; }    \
        _Pragma("unroll 1")                                                              \
        for (int i = 0; i < 8; ++i) {                                                    \
            float4 x = row[i];                                                           \
            const float* w = pw1 + (size_t)(p * 32 + i * 4) * HID + (ETA) * 32;          \
            const float4* w0 = reinterpret_cast<const float4*>(w);                       \
            const float4* w1 = reinterpret_cast<const float4*>(w + HID);                 \
            const float4* w2p = reinterpret_cast<const float4*>(w + 2 * HID);            \
            const float4* w3p = reinterpret_cast<const float4*>(w + 3 * HID);            \
            a0=fma4(x.x,w0[0],a0); a1=fma4(x.x,w0[1],a1); a2=fma4(x.x,w0[2],a2); a3=fma4(x.x,w0[3],a3); \
            a4=fma4(x.x,w0[4],a4); a5=fma4(x.x,w0[5],a5); a6=fma4(x.x,w0[6],a6); a7=fma4(x.x,w0[7],a7); \
            a0=fma4(x.y,w1[0],a0); a1=fma4(x.y,w1[1],a1); a2=fma4(x.y,w1[2],a2); a3=fma4(x.y,w1[3],a3); \
            a4=fma4(x.y,w1[4],a4); a5=fma4(x.y,w1[5],a5); a6=fma4(x.y,w1[6],a6); a7=fma4(x.y,w1[7],a7); \
            a0=fma4(x.z,w2p[0],a0); a1=fma4(x.z,w2p[1],a1); a2=fma4(x.z,w2p[2],a2); a3=fma4(x.z,w2p[3],a3); \
            a4=fma4(x.z,w2p[4],a4); a5=fma4(x.z,w2p[5],a5); a6=fma4(x.z,w2p[6],a6); a7=fma4(x.z,w2p[7],a7); \
            a0=fma4(x.w,w3p[0],a0); a1=fma4(x.w,w3p[1],a1); a2=fma4(x.w,w3p[2],a2); a3=fma4(x.w,w3p[3],a3); \
            a4=fma4(x.w,w3p[4],a4); a5=fma4(x.w,w3p[5],a5); a6=fma4(x.w,w3p[6],a6); a7=fma4(x.w,w3p[7],a7); \
        }                                                                                \
        {   /* capacity row (input dim 128), only lane 3 nonzero */                      \
            const float4* wc = reinterpret_cast<const float4*>(pw1 + (size_t)128 * HID + (ETA) * 32); \
            a0=fma4(cap,wc[0],a0); a1=fma4(cap,wc[1],a1); a2=fma4(cap,wc[2],a2); a3=fma4(cap,wc[3],a3); \
            a4=fma4(cap,wc[4],a4); a5=fma4(cap,wc[5],a5); a6=fma4(cap,wc[6],a6); a7=fma4(cap,wc[7],a7); \
        }                                                                                \
        /* butterfly over the 4-lane group */                                            \
        { _Pragma("unroll")                                                              \
          for (int m = 1; m <= 2; m <<= 1) {                                             \
            a0.x+=__shfl_xor(a0.x,m); a0.y+=__shfl_xor(a0.y,m); a0.z+=__shfl_xor(a0.z,m); a0.w+=__shfl_xor(a0.w,m); \
            a1.x+=__shfl_xor(a1.x,m); a1.y+=__shfl_xor(a1.y,m); a1.z+=__shfl_xor(a1.z,m); a1.w+=__shfl_xor(a1.w,m); \
            a2.x+=__shfl_xor(a2.x,m); a2.y+=__shfl_xor(a2.y,m); a2.z+=__shfl_xor(a2.z,m); a2.w+=__shfl_xor(a2.w,m); \
            a3.x+=__shfl_xor(a3.x,m); a3.y+=__shfl_xor(a3.y,m); a3.z+=__shfl_xor(a3.z,m); a3.w+=__shfl_xor(a3.w,m); \
            a4.x+=__shfl_xor(a4.x,m); a4.y+=__shfl_xor(a4.y,m); a4.z+=__shfl_xor(a4.z,m); a4.w+=__shfl_xor(a4.w,m); \
            a5.x+=__shfl_xor(a5.x,m); a5.y+=__shfl_xor(a5.y,m); a5.z+=__shfl_xor(a5.z,m); a5.w+=__shfl_xor(a5.w,m); \
            a6.x+=__shfl_xor(a6.x,m); a6.y+=__shfl_xor(a6.y,m); a6.z+=__shfl_xor(a6.z,m); a6.w+=__shfl_xor(a6.w,m); \
            a7.x+=__shfl_xor(a7.x,m); a7.y+=__shfl_xor(a7.y,m); a7.z+=__shfl_xor(a7.z,m); a7.w+=__shfl_xor(a7.w,m); \
        } }                                                                              \
        /* layer-2 partial over these 32 units, serial order (redundant on lanes) */     \
        { const float4* w2 = reinterpret_cast<const float4*>(pw2 + (ETA) * 32);          \
          float4 _w;                                                                     \
          _w=w2[0]; act=fmaf(silu_f(a0.x),_w.x,act); act=fmaf(silu_f(a0.y),_w.y,act); act=fmaf(silu_f(a0.z),_w.z,act); act=fmaf(silu_f(a0.w),_w.w,act); \
          _w=w2[1]; act=fmaf(silu_f(a1.x),_w.x,act); act=fmaf(silu_f(a1.y),_w.y,act); act=fmaf(silu_f(a1.z),_w.z,act); act=fmaf(silu_f(a1.w),_w.w,act); \
          _w=w2[2]; act=fmaf(silu_f(a2.x),_w.x,act); act=fmaf(silu_f(a2.y),_w.y,act); act=fmaf(silu_f(a2.z),_w.z,act); act=fmaf(silu_f(a2.w),_w.w,act); \
          _w=w2[3]; act=fmaf(silu_f(a3.x),_w.x,act); act=fmaf(silu_f(a3.y),_w.y,act); act=fmaf(silu_f(a3.z),_w.z,act); act=fmaf(silu_f(a3.w),_w.w,act); \
          _w=w2[4]; act=fmaf(silu_f(a4.x),_w.x,act); act=fmaf(silu_f(a4.y),_w.y,act); act=fmaf(silu_f(a4.z),_w.z,act); act=fmaf(silu_f(a4.w),_w.w,act); \
          _w=w2[5]; act=fmaf(silu_f(a5.x),_w.x,act); act=fmaf(silu_f(a5.y),_w.y,act); act=fmaf(silu_f(a5.z),_w.z,act); act=fmaf(silu_f(a5.w),_w.w,act); \
          _w=w2[6]; act=fmaf(silu_f(a6.x),_w.x,act); act=fmaf(silu_f(a6.y),_w.y,act); act=fmaf(silu_f(a6.z),_w.z,act); act=fmaf(silu_f(a6.w),_w.w,act); \
          _w=w2[7]; act=fmaf(silu_f(a7.x),_w.x,act); act=fmaf(silu_f(a7.y),_w.y,act); act=fmaf(silu_f(a7.z),_w.z,act); act=fmaf(silu_f(a7.w),_w.w,act); \
        }                                                                                \
    }

    PASS(0)
    PASS(1)
#undef PASS

    if (p == 0) {
        unsigned m = (act > 0.0f) ? 1u : 0u;
        mask[n] = m;
        outmask[n] = m ? 1.0f : 0.0f;
        if (m) {
            unsigned slot = atomicAdd(&counters[1], 1u);
            mlist[slot] = n;
        }
    }
}

// compact edges with emask = mask[src] && !mask[tgt]
__global__ void k_compact(const int* __restrict__ ei, const unsigned* __restrict__ mask,
                          unsigned* __restrict__ act_eid, unsigned* __restrict__ counters, int E) {
    int e = blockIdx.x * blockDim.x + threadIdx.x;
    if (e >= E) return;
    int s = ei[e], t = ei[E + e];
    if (mask[s] && !mask[t]) {
        unsigned slot = atomicAdd(&counters[0], 1u);
        act_eid[slot] = (unsigned)e;
    }
}

// ---- redistribution MLP: 2 lanes per active edge, split-K, all f32 ----
__global__ __launch_bounds__(256, 4) void k_edge_mlp(
    const float* __restrict__ states, const int* __restrict__ ei,
    const float* __restrict__ rw1, const float* __restrict__ rb1,
    const float* __restrict__ rw2, const float* __restrict__ rb2,
    const float* __restrict__ rw3, const float* __restrict__ rb3,
    const unsigned* __restrict__ act_eid, const unsigned* __restrict__ counters,
    float* __restrict__ rawbuf, unsigned* __restrict__ segmax, int E) {
    unsigned t = blockIdx.x * 256u + threadIdx.x;
    unsigned grp = t >> 1, p = t & 1u;
    if (grp >= counters[0]) return;
    int e = (int)act_eid[grp];
    int s = ei[e], tg = ei[E + e];
    // lane p gathers one row (its k-half): p=0 -> src (k 0..127), p=1 -> tgt (k 128..255)
    const float4* row = reinterpret_cast<const float4*>(states + (size_t)(p ? tg : s) * D);
    float bs = (p == 0) ? 1.0f : 0.0f;
    float4 h0, h1, h2, h3, h4, h5, h6, h7, h8, h9, h10, h11, h12, h13, h14, h15;
    { const float4* b4 = reinterpret_cast<const float4*>(rb1);
      h0 = b4[0]; h1 = b4[1]; h2 = b4[2]; h3 = b4[3];
      h4 = b4[4]; h5 = b4[5]; h6 = b4[6]; h7 = b4[7];
      h8 = b4[8]; h9 = b4[9]; h10 = b4[10]; h11 = b4[11];
      h12 = b4[12]; h13 = b4[13]; h14 = b4[14]; h15 = b4[15];
#define SCL(v) v.x *= bs; v.y *= bs; v.z *= bs; v.w *= bs;
      SCL(h0) SCL(h1) SCL(h2) SCL(h3) SCL(h4) SCL(h5) SCL(h6) SCL(h7)
      SCL(h8) SCL(h9) SCL(h10) SCL(h11) SCL(h12) SCL(h13) SCL(h14) SCL(h15)
#undef SCL
    }
#define ACC16(xv, wp) { const float4* _w4 = reinterpret_cast<const float4*>(wp); \
    h0  = fma4(xv, _w4[0],  h0);  h1  = fma4(xv, _w4[1],  h1);  \
    h2  = fma4(xv, _w4[2],  h2);  h3  = fma4(xv, _w4[3],  h3);  \
    h4  = fma4(xv, _w4[4],  h4);  h5  = fma4(xv, _w4[5],  h5);  \
    h6  = fma4(xv, _w4[6],  h6);  h7  = fma4(xv, _w4[7],  h7);  \
    h8  = fma4(xv, _w4[8],  h8);  h9  = fma4(xv, _w4[9],  h9);  \
    h10 = fma4(xv, _w4[10], h10); h11 = fma4(xv, _w4[11], h11); \
    h12 = fma4(xv, _w4[12], h12); h13 = fma4(xv, _w4[13], h13); \
    h14 = fma4(xv, _w4[14], h14); h15 = fma4(xv, _w4[15], h15); }
    const float* wbase = rw1 + (size_t)p * D * HID;   // this lane's 128 k rows
#pragma unroll 1
    for (int i = 0; i < 32; ++i) {
        float4 x = row[i];
        const float* w = wbase + (size_t)(4 * i) * HID;
        ACC16(x.x, w) ACC16(x.y, w + HID) ACC16(x.z, w + 2 * HID) ACC16(x.w, w + 3 * HID)
    }
#undef ACC16
    // exchange partial h across the lane pair -> both lanes hold full pre-activation
#define XCH1(v) { v.x += __shfl_xor(v.x, 1); v.y += __shfl_xor(v.y, 1); \
                  v.z += __shfl_xor(v.z, 1); v.w += __shfl_xor(v.w, 1); }
    XCH1(h0) XCH1(h1) XCH1(h2) XCH1(h3) XCH1(h4) XCH1(h5) XCH1(h6) XCH1(h7)
    XCH1(h8) XCH1(h9) XCH1(h10) XCH1(h11) XCH1(h12) XCH1(h13) XCH1(h14) XCH1(h15)
#undef XCH1
    h0 = silu4(h0); h1 = silu4(h1); h2 = silu4(h2); h3 = silu4(h3);
    h4 = silu4(h4); h5 = silu4(h5); h6 = silu4(h6); h7 = silu4(h7);
    h8 = silu4(h8); h9 = silu4(h9); h10 = silu4(h10); h11 = silu4(h11);
    h12 = silu4(h12); h13 = silu4(h13); h14 = silu4(h14); h15 = silu4(h15);
    // layer 2 (f32): lane p computes h2 units j in [32p, 32p+32)
    float4 b0, b1, b2, b3, b4, b5, b6, b7;
    { const float4* bb = reinterpret_cast<const float4*>(rb2) + p * 8;
      b0 = bb[0]; b1 = bb[1]; b2 = bb[2]; b3 = bb[3];
      b4 = bb[4]; b5 = bb[5]; b6 = bb[6]; b7 = bb[7]; }
#define L2STEP(hc, k) { const float4* _w = reinterpret_cast<const float4*>(rw2 + (size_t)(k) * HID) + p * 8; \
    b0 = fma4(hc, _w[0], b0); b1 = fma4(hc, _w[1], b1); b2 = fma4(hc, _w[2], b2); b3 = fma4(hc, _w[3], b3); \
    b4 = fma4(hc, _w[4], b4); b5 = fma4(hc, _w[5], b5); b6 = fma4(hc, _w[6], b6); b7 = fma4(hc, _w[7], b7); }
#define L2G(hr, kb) L2STEP(hr.x, kb) L2STEP(hr.y, (kb)+1) L2STEP(hr.z, (kb)+2) L2STEP(hr.w, (kb)+3)
    L2G(h0, 0)   L2G(h1, 4)   L2G(h2, 8)   L2G(h3, 12)
    L2G(h4, 16)  L2G(h5, 20)  L2G(h6, 24)  L2G(h7, 28)
    L2G(h8, 32)  L2G(h9, 36)  L2G(h10, 40) L2G(h11, 44)
    L2G(h12, 48) L2G(h13, 52) L2G(h14, 56) L2G(h15, 60)
#undef L2G
#undef L2STEP
    b0 = silu4(b0); b1 = silu4(b1); b2 = silu4(b2); b3 = silu4(b3);
    b4 = silu4(b4); b5 = silu4(b5); b6 = silu4(b6); b7 = silu4(b7);
    // layer 3: partial dot over this lane's 32 units, then pair-reduce
    const float4* w3 = reinterpret_cast<const float4*>(rw3) + p * 8;
    float part = ((dot4(b0, w3[0]) + dot4(b1, w3[1])) + (dot4(b2, w3[2]) + dot4(b3, w3[3])))
               + ((dot4(b4, w3[4]) + dot4(b5, w3[5])) + (dot4(b6, w3[6]) + dot4(b7, w3[7])));
    part += __shfl_xor(part, 1);
    if (p == 0) {
        float raw = part + rb3[0];
        rawbuf[grp] = raw;
        atomicMax(&segmax[s], fenc(raw));
    }
}

__global__ void k_exp(const int* __restrict__ ei, const unsigned* __restrict__ act_eid,
                      const unsigned* __restrict__ counters, const unsigned* __restrict__ segmax,
                      float* __restrict__ rawbuf, float* __restrict__ denom, int E) {
    unsigned t = blockIdx.x * blockDim.x + threadIdx.x;
    if (t >= counters[0]) return;
    int e = (int)act_eid[t];
    int s = ei[e];
    float ev = expf(rawbuf[t] - fdec(segmax[s]));
    rawbuf[t] = ev;
    atomicAdd(&denom[s], ev);
}

// wave-per-active-edge: out[tgt] += w * states[src]
__global__ __launch_bounds__(256) void k_scatter(
    const float* __restrict__ states, const int* __restrict__ ei,
    const unsigned* __restrict__ act_eid, const unsigned* __restrict__ counters,
    const float* __restrict__ rawbuf, const float* __restrict__ denom,
    float* __restrict__ out, int E) {
    unsigned w = blockIdx.x * (blockDim.x >> 6) + (threadIdx.x >> 6);
    unsigned lane = threadIdx.x & 63u;
    if (w >= counters[0]) return;
    int e = (int)act_eid[w];
    int s = ei[e], tg = ei[E + e];
    float wt = rawbuf[w] / denom[s];
    const float* srow = states + (size_t)s * D;
    float* orow = out + (size_t)tg * D;
    atomicAdd(&orow[lane], wt * srow[lane]);
    atomicAdd(&orow[lane + 64], wt * srow[lane + 64]);
}

// failed nodes: out = tanh(redist @ tw + tb) * 0.05
__global__ __launch_bounds__(256) void k_jump(
    const float* __restrict__ tw, const float* __restrict__ tb,
    const unsigned* __restrict__ mlist, const unsigned* __restrict__ counters,
    float* __restrict__ out) {
    __shared__ float xs[2][D];
    unsigned g = threadIdx.x >> 7;
    unsigned d = threadIdx.x & 127u;
    unsigned slot = blockIdx.x * 2 + g;
    bool valid = slot < counters[1];
    int n = valid ? (int)mlist[slot] : 0;
    float* row = out + (size_t)n * D;
    if (valid) xs[g][d] = row[d];
    __syncthreads();
    if (!valid) return;
    float acc = tb[d];
    const float* ws = &xs[g][0];
    for (int k = 0; k < D; k += 4) {
        acc = fmaf(ws[k + 0], tw[(k + 0) * D + d], acc);
        acc = fmaf(ws[k + 1], tw[(k + 1) * D + d], acc);
        acc = fmaf(ws[k + 2], tw[(k + 2) * D + d], acc);
        acc = fmaf(ws[k + 3], tw[(k + 3) * D + d], acc);
    }
    row[d] = tanhf(acc) * 0.05f;
}

extern "C" void kernel_launch(void* const* d_in, const int* in_sizes, int n_in,
                              void* d_out, int out_size, void* d_ws, size_t ws_size,
                              hipStream_t stream) {
    const float* states = (const float*)d_in[0];
    const float* caps   = (const float*)d_in[1];
    const int*   ei     = (const int*)d_in[2];
    const float* rw1 = (const float*)d_in[3];  const float* rb1 = (const float*)d_in[4];
    const float* rw2 = (const float*)d_in[5];  const float* rb2 = (const float*)d_in[6];
    const float* rw3 = (const float*)d_in[7];  const float* rb3 = (const float*)d_in[8];
    const float* pw1 = (const float*)d_in[9];  const float* pb1 = (const float*)d_in[10];
    const float* pw2 = (const float*)d_in[11]; const float* pb2 = (const float*)d_in[12];
    const float* tw  = (const float*)d_in[13]; const float* tb  = (const float*)d_in[14];
    const int N = in_sizes[1];
    const int E = in_sizes[2] / 2;
    float* out = (float*)d_out;

    // ws layout (u32 units): [0..3] counters | segmax N | denom N | mask N | mlist N | act_eid E | rawbuf E
    unsigned* ws       = (unsigned*)d_ws;
    unsigned* counters = ws;
    unsigned* segmax   = ws + 4;
    float*    denom    = (float*)(ws + 4 + (size_t)N);
    unsigned* mask     = ws + 4 + 2 * (size_t)N;
    unsigned* mlist    = ws + 4 + 3 * (size_t)N;
    unsigned* act_eid  = ws + 4 + 4 * (size_t)N;
    float*    rawbuf   = (float*)(ws + 4 + 4 * (size_t)N + (size_t)E);

    hipMemsetAsync(d_ws, 0, (size_t)(4 + 2 * (size_t)N) * 4, stream);

    const int n4 = N * D / 4;
    k_copy<<<(n4 + 255) / 256, 256, 0, stream>>>(states, out, n4);
    k_protect<<<(4 * N + 255) / 256, 256, 0, stream>>>(states, caps, pw1, pb1, pw2, pb2,
                                                       mask, mlist, counters, out + (size_t)N * D, N);
    k_compact<<<(E + 255) / 256, 256, 0, stream>>>(ei, mask, act_eid, counters, E);
    k_edge_mlp<<<(2 * E + 255) / 256, 256, 0, stream>>>(states, ei, rw1, rb1, rw2, rb2, rw3, rb3,
                                                        act_eid, counters, rawbuf, segmax, E);
    k_exp<<<(E + 255) / 256, 256, 0, stream>>>(ei, act_eid, counters, segmax, rawbuf, denom, E);
    k_scatter<<<(E + 3) / 4, 256, 0, stream>>>(states, ei, act_eid, counters, rawbuf, denom, out, E);
    k_jump<<<(N + 1) / 2, 256, 0, stream>>>(tw, tb, mlist, counters, out);
}

// Round 6
// 490.116 us; speedup vs baseline: 2.4901x; 2.4901x over previous
//
#include <hip/hip_runtime.h>
#include <cmath>

#define D 128
#define HID 64

__device__ __forceinline__ float silu_f(float x) { return x / (1.0f + expf(-x)); }

__device__ __forceinline__ float4 fma4(float a, float4 w, float4 c) {
    c.x = fmaf(a, w.x, c.x); c.y = fmaf(a, w.y, c.y);
    c.z = fmaf(a, w.z, c.z); c.w = fmaf(a, w.w, c.w);
    return c;
}
__device__ __forceinline__ float4 silu4(float4 v) {
    v.x = silu_f(v.x); v.y = silu_f(v.y); v.z = silu_f(v.z); v.w = silu_f(v.w);
    return v;
}

// order-preserving float <-> uint encode for atomicMax on floats
__device__ __forceinline__ unsigned fenc(float f) {
    unsigned u = __float_as_uint(f);
    return (u & 0x80000000u) ? ~u : (u | 0x80000000u);
}
__device__ __forceinline__ float fdec(unsigned e) {
    unsigned u = (e & 0x80000000u) ? (e & 0x7FFFFFFFu) : ~e;
    return __uint_as_float(u);
}

// accumulate 64 hidden units (16 named float4) with one input scalar, weights at wp
#define ACC16(xv, wp) { const float4* _w4 = reinterpret_cast<const float4*>(wp); \
    h0  = fma4(xv, _w4[0],  h0);  h1  = fma4(xv, _w4[1],  h1);  \
    h2  = fma4(xv, _w4[2],  h2);  h3  = fma4(xv, _w4[3],  h3);  \
    h4  = fma4(xv, _w4[4],  h4);  h5  = fma4(xv, _w4[5],  h5);  \
    h6  = fma4(xv, _w4[6],  h6);  h7  = fma4(xv, _w4[7],  h7);  \
    h8  = fma4(xv, _w4[8],  h8);  h9  = fma4(xv, _w4[9],  h9);  \
    h10 = fma4(xv, _w4[10], h10); h11 = fma4(xv, _w4[11], h11); \
    h12 = fma4(xv, _w4[12], h12); h13 = fma4(xv, _w4[13], h13); \
    h14 = fma4(xv, _w4[14], h14); h15 = fma4(xv, _w4[15], h15); }

#define INIT16(bp) { const float4* _b4 = reinterpret_cast<const float4*>(bp); \
    h0 = _b4[0]; h1 = _b4[1]; h2 = _b4[2]; h3 = _b4[3]; \
    h4 = _b4[4]; h5 = _b4[5]; h6 = _b4[6]; h7 = _b4[7]; \
    h8 = _b4[8]; h9 = _b4[9]; h10 = _b4[10]; h11 = _b4[11]; \
    h12 = _b4[12]; h13 = _b4[13]; h14 = _b4[14]; h15 = _b4[15]; }

#define SILU16() { h0 = silu4(h0); h1 = silu4(h1); h2 = silu4(h2); h3 = silu4(h3); \
    h4 = silu4(h4); h5 = silu4(h5); h6 = silu4(h6); h7 = silu4(h7); \
    h8 = silu4(h8); h9 = silu4(h9); h10 = silu4(h10); h11 = silu4(h11); \
    h12 = silu4(h12); h13 = silu4(h13); h14 = silu4(h14); h15 = silu4(h15); }

// dot with 4 partial sums, k%4 -> s0..s3 (matches r1/r2 ordering)
__device__ __forceinline__ void fd4(float4 h, float4 w, float& s0, float& s1, float& s2, float& s3) {
    s0 = fmaf(h.x, w.x, s0); s1 = fmaf(h.y, w.y, s1);
    s2 = fmaf(h.z, w.z, s2); s3 = fmaf(h.w, w.w, s3);
}
#define FD16(w4) { fd4(h0, w4[0], s0, s1, s2, s3);  fd4(h1, w4[1], s0, s1, s2, s3);  \
    fd4(h2, w4[2], s0, s1, s2, s3);  fd4(h3, w4[3], s0, s1, s2, s3);  \
    fd4(h4, w4[4], s0, s1, s2, s3);  fd4(h5, w4[5], s0, s1, s2, s3);  \
    fd4(h6, w4[6], s0, s1, s2, s3);  fd4(h7, w4[7], s0, s1, s2, s3);  \
    fd4(h8, w4[8], s0, s1, s2, s3);  fd4(h9, w4[9], s0, s1, s2, s3);  \
    fd4(h10, w4[10], s0, s1, s2, s3); fd4(h11, w4[11], s0, s1, s2, s3); \
    fd4(h12, w4[12], s0, s1, s2, s3); fd4(h13, w4[13], s0, s1, s2, s3); \
    fd4(h14, w4[14], s0, s1, s2, s3); fd4(h15, w4[15], s0, s1, s2, s3); }

// serial silu-dot (matches r1/r2 serial order for mask stability)
__device__ __forceinline__ float accdot(float4 h, float4 w, float act) {
    act = fmaf(silu_f(h.x), w.x, act);
    act = fmaf(silu_f(h.y), w.y, act);
    act = fmaf(silu_f(h.z), w.z, act);
    act = fmaf(silu_f(h.w), w.w, act);
    return act;
}

__global__ void k_copy(const float* __restrict__ src, float* __restrict__ dst, int n4) {
    int i = blockIdx.x * blockDim.x + threadIdx.x;
    if (i < n4) reinterpret_cast<float4*>(dst)[i] = reinterpret_cast<const float4*>(src)[i];
}

// ---- protection net: 1 wave per block, 1 lane per node, pw1 staged in LDS ----
__global__ __launch_bounds__(64) void k_protect(
    const float* __restrict__ states, const float* __restrict__ caps,
    const float* __restrict__ pw1, const float* __restrict__ pb1,
    const float* __restrict__ pw2, const float* __restrict__ pb2,
    unsigned* __restrict__ mask, unsigned* __restrict__ mlist,
    unsigned* __restrict__ counters, float* __restrict__ outmask, int N) {
    __shared__ float wl[64 * 64];                 // 16KB slab
    unsigned n = blockIdx.x * 64u + threadIdx.x;
    bool active = n < (unsigned)N;
    unsigned nq = active ? n : (unsigned)(N - 1);
    const float4* row = reinterpret_cast<const float4*>(states + (size_t)nq * D);
    float4 h0, h1, h2, h3, h4, h5, h6, h7, h8, h9, h10, h11, h12, h13, h14, h15;
    INIT16(pb1);
    for (int slab = 0; slab < 2; ++slab) {
        if (slab) __syncthreads();
        {   // stage 4096 floats: 16 float4 per thread, coalesced
            const float4* src4 = reinterpret_cast<const float4*>(pw1 + slab * 4096);
            float4* dst4 = reinterpret_cast<float4*>(wl);
#pragma unroll
            for (int q = 0; q < 16; ++q) dst4[threadIdx.x + q * 64] = src4[threadIdx.x + q * 64];
        }
        __syncthreads();
        const float4* r = row + slab * 16;
#pragma unroll 1
        for (int i = 0; i < 16; ++i) {
            float4 x = r[i];
            const float* w = wl + (size_t)(i * 4) * HID;
            ACC16(x.x, w) ACC16(x.y, w + HID) ACC16(x.z, w + 2 * HID) ACC16(x.w, w + 3 * HID)
        }
    }
    {   // capacity row (input dim 128), uniform global reads (L1-hot)
        float xv = caps[nq];
        ACC16(xv, pw1 + (size_t)128 * HID)
    }
    // layer 2: serial silu-dot, uniform global reads of pw2
    const float4* w2 = reinterpret_cast<const float4*>(pw2);
    float act = pb2[0];
    act = accdot(h0, w2[0], act);   act = accdot(h1, w2[1], act);
    act = accdot(h2, w2[2], act);   act = accdot(h3, w2[3], act);
    act = accdot(h4, w2[4], act);   act = accdot(h5, w2[5], act);
    act = accdot(h6, w2[6], act);   act = accdot(h7, w2[7], act);
    act = accdot(h8, w2[8], act);   act = accdot(h9, w2[9], act);
    act = accdot(h10, w2[10], act); act = accdot(h11, w2[11], act);
    act = accdot(h12, w2[12], act); act = accdot(h13, w2[13], act);
    act = accdot(h14, w2[14], act); act = accdot(h15, w2[15], act);
    if (active) {
        unsigned m = (act > 0.0f) ? 1u : 0u;
        mask[n] = m;
        outmask[n] = m ? 1.0f : 0.0f;
        if (m) {
            unsigned slot = atomicAdd(&counters[1], 1u);
            mlist[slot] = n;
        }
    }
}

// compact edges with emask = mask[src] && !mask[tgt]
__global__ void k_compact(const int* __restrict__ ei, const unsigned* __restrict__ mask,
                          unsigned* __restrict__ act_eid, unsigned* __restrict__ counters, int E) {
    int e = blockIdx.x * blockDim.x + threadIdx.x;
    if (e >= E) return;
    int s = ei[e], t = ei[E + e];
    if (mask[s] && !mask[t]) {
        unsigned slot = atomicAdd(&counters[0], 1u);
        act_eid[slot] = (unsigned)e;
    }
}

// ---- redistribution MLP: 1 lane per active edge, weights staged in LDS ----
__global__ __launch_bounds__(256) void k_edge_mlp(
    const float* __restrict__ states, const int* __restrict__ ei,
    const float* __restrict__ rw1, const float* __restrict__ rb1,
    const float* __restrict__ rw2, const float* __restrict__ rb2,
    const float* __restrict__ rw3, const float* __restrict__ rb3,
    const unsigned* __restrict__ act_eid, const unsigned* __restrict__ counters,
    float* __restrict__ rawbuf, unsigned* __restrict__ segmax, int E) {
    __shared__ float wl[64 * 68];                 // slab (first 4096) / rw2T (stride 68, 16B-aligned)
    unsigned cnt = counters[0];
    if (cnt == 0) return;
    if (blockIdx.x * 256u >= cnt) return;         // whole block inactive (uniform)
    unsigned grp = blockIdx.x * 256u + threadIdx.x;
    bool active = grp < cnt;
    unsigned gq = active ? grp : (cnt - 1);
    int e = (int)act_eid[gq];
    int s = ei[e], tg = ei[E + e];
    const float4* rowA = reinterpret_cast<const float4*>(states + (size_t)s * D);
    const float4* rowB = reinterpret_cast<const float4*>(states + (size_t)tg * D);
    float4 h0, h1, h2, h3, h4, h5, h6, h7, h8, h9, h10, h11, h12, h13, h14, h15;
    INIT16(rb1);
    // layer 1: K=256 in 4 slabs of 64 rows (16KB each)
    for (int slab = 0; slab < 4; ++slab) {
        if (slab) __syncthreads();
        {   // stage 4096 floats: 4 float4 per thread, coalesced
            const float4* src4 = reinterpret_cast<const float4*>(rw1 + (size_t)slab * 4096);
            float4* dst4 = reinterpret_cast<float4*>(wl);
            dst4[threadIdx.x]       = src4[threadIdx.x];
            dst4[threadIdx.x + 256] = src4[threadIdx.x + 256];
            dst4[threadIdx.x + 512] = src4[threadIdx.x + 512];
            dst4[threadIdx.x + 768] = src4[threadIdx.x + 768];
        }
        __syncthreads();
        const float4* row = (slab < 2) ? (rowA + slab * 16) : (rowB + (slab - 2) * 16);
#pragma unroll 1
        for (int i = 0; i < 16; ++i) {
            float4 x = row[i];
            const float* w = wl + (size_t)(i * 4) * HID;
            ACC16(x.x, w) ACC16(x.y, w + HID) ACC16(x.z, w + 2 * HID) ACC16(x.w, w + 3 * HID)
        }
    }
    SILU16();
    // stage rw2 transposed: wl[j*68 + k] = rw2[k*64 + j]
    __syncthreads();
#pragma unroll
    for (int q = 0; q < 16; ++q) {
        int i = (int)threadIdx.x + q * 256;
        wl[(i & 63) * 68 + (i >> 6)] = rw2[i];
    }
    __syncthreads();
    // layers 2+3 fused: per j, dot(h, rw2T[j]) -> silu -> raw += h2*rw3[j]
    float raw = rb3[0];
#pragma unroll 1
    for (int j = 0; j < HID; ++j) {
        const float4* w4 = reinterpret_cast<const float4*>(wl + j * 68);
        float s0 = rb2[j], s1 = 0.f, s2 = 0.f, s3 = 0.f;
        FD16(w4);
        float h2v = silu_f((s0 + s1) + (s2 + s3));
        raw = fmaf(h2v, rw3[j], raw);
    }
    if (active) {
        rawbuf[grp] = raw;
        atomicMax(&segmax[s], fenc(raw));
    }
}

__global__ void k_exp(const int* __restrict__ ei, const unsigned* __restrict__ act_eid,
                      const unsigned* __restrict__ counters, const unsigned* __restrict__ segmax,
                      float* __restrict__ rawbuf, float* __restrict__ denom, int E) {
    unsigned t = blockIdx.x * blockDim.x + threadIdx.x;
    if (t >= counters[0]) return;
    int e = (int)act_eid[t];
    int s = ei[e];
    float ev = expf(rawbuf[t] - fdec(segmax[s]));
    rawbuf[t] = ev;
    atomicAdd(&denom[s], ev);
}

// wave-per-active-edge: out[tgt] += w * states[src]
__global__ __launch_bounds__(256) void k_scatter(
    const float* __restrict__ states, const int* __restrict__ ei,
    const unsigned* __restrict__ act_eid, const unsigned* __restrict__ counters,
    const float* __restrict__ rawbuf, const float* __restrict__ denom,
    float* __restrict__ out, int E) {
    unsigned w = blockIdx.x * (blockDim.x >> 6) + (threadIdx.x >> 6);
    unsigned lane = threadIdx.x & 63u;
    if (w >= counters[0]) return;
    int e = (int)act_eid[w];
    int s = ei[e], tg = ei[E + e];
    float wt = rawbuf[w] / denom[s];
    const float* srow = states + (size_t)s * D;
    float* orow = out + (size_t)tg * D;
    atomicAdd(&orow[lane], wt * srow[lane]);
    atomicAdd(&orow[lane + 64], wt * srow[lane + 64]);
}

// failed nodes: out = tanh(redist @ tw + tb) * 0.05
// 8 nodes per 256-thread block: thread (d, r) accumulates 4 nodes, tw element reused 4x
__global__ __launch_bounds__(256) void k_jump(
    const float* __restrict__ tw, const float* __restrict__ tb,
    const unsigned* __restrict__ mlist, const unsigned* __restrict__ counters,
    float* __restrict__ out) {
    __shared__ float xs[8][D];
    unsigned cnt = counters[1];
    unsigned base = blockIdx.x * 8u;
    if (base >= cnt || cnt == 0) return;          // uniform
    unsigned tid = threadIdx.x;
    unsigned d = tid & 127u, r = tid >> 7;        // r in {0,1}
    {   // stage 8 rows (clamped): 32 threads per row, float4 each
        unsigned j = tid >> 5;
        unsigned c = (tid & 31u) * 4u;
        unsigned slot = base + j; if (slot >= cnt) slot = cnt - 1;
        int nn = (int)mlist[slot];
        *reinterpret_cast<float4*>(&xs[j][c]) =
            *reinterpret_cast<const float4*>(&out[(size_t)nn * D + c]);
    }
    __syncthreads();
    float tbd = tb[d];
    float a0 = tbd, a1 = tbd, a2 = tbd, a3 = tbd;
    const float* x0 = &xs[r * 4 + 0][0];
    const float* x1 = &xs[r * 4 + 1][0];
    const float* x2 = &xs[r * 4 + 2][0];
    const float* x3 = &xs[r * 4 + 3][0];
#pragma unroll 1
    for (int k = 0; k < D; ++k) {
        float w = tw[(size_t)k * D + d];
        a0 = fmaf(x0[k], w, a0);
        a1 = fmaf(x1[k], w, a1);
        a2 = fmaf(x2[k], w, a2);
        a3 = fmaf(x3[k], w, a3);
    }
    float res[4] = {a0, a1, a2, a3};
#pragma unroll
    for (int j2 = 0; j2 < 4; ++j2) {
        unsigned slot = base + r * 4 + j2;
        if (slot < cnt) {
            int nn = (int)mlist[slot];
            out[(size_t)nn * D + d] = tanhf(res[j2]) * 0.05f;
        }
    }
}

extern "C" void kernel_launch(void* const* d_in, const int* in_sizes, int n_in,
                              void* d_out, int out_size, void* d_ws, size_t ws_size,
                              hipStream_t stream) {
    const float* states = (const float*)d_in[0];
    const float* caps   = (const float*)d_in[1];
    const int*   ei     = (const int*)d_in[2];
    const float* rw1 = (const float*)d_in[3];  const float* rb1 = (const float*)d_in[4];
    const float* rw2 = (const float*)d_in[5];  const float* rb2 = (const float*)d_in[6];
    const float* rw3 = (const float*)d_in[7];  const float* rb3 = (const float*)d_in[8];
    const float* pw1 = (const float*)d_in[9];  const float* pb1 = (const float*)d_in[10];
    const float* pw2 = (const float*)d_in[11]; const float* pb2 = (const float*)d_in[12];
    const float* tw  = (const float*)d_in[13]; const float* tb  = (const float*)d_in[14];
    const int N = in_sizes[1];
    const int E = in_sizes[2] / 2;
    float* out = (float*)d_out;

    // ws layout (u32 units): [0..3] counters | segmax N | denom N | mask N | mlist N | act_eid E | rawbuf E
    unsigned* ws       = (unsigned*)d_ws;
    unsigned* counters = ws;
    unsigned* segmax   = ws + 4;
    float*    denom    = (float*)(ws + 4 + (size_t)N);
    unsigned* mask     = ws + 4 + 2 * (size_t)N;
    unsigned* mlist    = ws + 4 + 3 * (size_t)N;
    unsigned* act_eid  = ws + 4 + 4 * (size_t)N;
    float*    rawbuf   = (float*)(ws + 4 + 4 * (size_t)N + (size_t)E);

    hipMemsetAsync(d_ws, 0, (size_t)(4 + 2 * (size_t)N) * 4, stream);

    const int n4 = N * D / 4;
    k_copy<<<(n4 + 255) / 256, 256, 0, stream>>>(states, out, n4);
    k_protect<<<(N + 63) / 64, 64, 0, stream>>>(states, caps, pw1, pb1, pw2, pb2,
                                                mask, mlist, counters, out + (size_t)N * D, N);
    k_compact<<<(E + 255) / 256, 256, 0, stream>>>(ei, mask, act_eid, counters, E);
    k_edge_mlp<<<(E + 255) / 256, 256, 0, stream>>>(states, ei, rw1, rb1, rw2, rb2, rw3, rb3,
                                                    act_eid, counters, rawbuf, segmax, E);
    k_exp<<<(E + 255) / 256, 256, 0, stream>>>(ei, act_eid, counters, segmax, rawbuf, denom, E);
    k_scatter<<<(E + 3) / 4, 256, 0, stream>>>(states, ei, act_eid, counters, rawbuf, denom, out, E);
    k_jump<<<(N + 7) / 8, 256, 0, stream>>>(tw, tb, mlist, counters, out);
}

// Round 7
// 486.622 us; speedup vs baseline: 2.5080x; 1.0072x over previous
//
#include <hip/hip_runtime.h>
#include <cmath>

#define D 128
#define HID 64

__device__ __forceinline__ float silu_f(float x) { return x / (1.0f + expf(-x)); }

__device__ __forceinline__ float4 fma4(float a, float4 w, float4 c) {
    c.x = fmaf(a, w.x, c.x); c.y = fmaf(a, w.y, c.y);
    c.z = fmaf(a, w.z, c.z); c.w = fmaf(a, w.w, c.w);
    return c;
}
__device__ __forceinline__ float4 silu4(float4 v) {
    v.x = silu_f(v.x); v.y = silu_f(v.y); v.z = silu_f(v.z); v.w = silu_f(v.w);
    return v;
}

// order-preserving float <-> uint encode for atomicMax on floats
__device__ __forceinline__ unsigned fenc(float f) {
    unsigned u = __float_as_uint(f);
    return (u & 0x80000000u) ? ~u : (u | 0x80000000u);
}
__device__ __forceinline__ float fdec(unsigned e) {
    unsigned u = (e & 0x80000000u) ? (e & 0x7FFFFFFFu) : ~e;
    return __uint_as_float(u);
}

// accumulate 64 hidden units (16 named float4) with one input scalar, weights at wp
#define ACC16(xv, wp) { const float4* _w4 = reinterpret_cast<const float4*>(wp); \
    h0  = fma4(xv, _w4[0],  h0);  h1  = fma4(xv, _w4[1],  h1);  \
    h2  = fma4(xv, _w4[2],  h2);  h3  = fma4(xv, _w4[3],  h3);  \
    h4  = fma4(xv, _w4[4],  h4);  h5  = fma4(xv, _w4[5],  h5);  \
    h6  = fma4(xv, _w4[6],  h6);  h7  = fma4(xv, _w4[7],  h7);  \
    h8  = fma4(xv, _w4[8],  h8);  h9  = fma4(xv, _w4[9],  h9);  \
    h10 = fma4(xv, _w4[10], h10); h11 = fma4(xv, _w4[11], h11); \
    h12 = fma4(xv, _w4[12], h12); h13 = fma4(xv, _w4[13], h13); \
    h14 = fma4(xv, _w4[14], h14); h15 = fma4(xv, _w4[15], h15); }

#define INIT16(bp) { const float4* _b4 = reinterpret_cast<const float4*>(bp); \
    h0 = _b4[0]; h1 = _b4[1]; h2 = _b4[2]; h3 = _b4[3]; \
    h4 = _b4[4]; h5 = _b4[5]; h6 = _b4[6]; h7 = _b4[7]; \
    h8 = _b4[8]; h9 = _b4[9]; h10 = _b4[10]; h11 = _b4[11]; \
    h12 = _b4[12]; h13 = _b4[13]; h14 = _b4[14]; h15 = _b4[15]; }

#define SILU16() { h0 = silu4(h0); h1 = silu4(h1); h2 = silu4(h2); h3 = silu4(h3); \
    h4 = silu4(h4); h5 = silu4(h5); h6 = silu4(h6); h7 = silu4(h7); \
    h8 = silu4(h8); h9 = silu4(h9); h10 = silu4(h10); h11 = silu4(h11); \
    h12 = silu4(h12); h13 = silu4(h13); h14 = silu4(h14); h15 = silu4(h15); }

// dot with 4 partial sums, k%4 -> s0..s3 (matches r1/r2 ordering)
__device__ __forceinline__ void fd4(float4 h, float4 w, float& s0, float& s1, float& s2, float& s3) {
    s0 = fmaf(h.x, w.x, s0); s1 = fmaf(h.y, w.y, s1);
    s2 = fmaf(h.z, w.z, s2); s3 = fmaf(h.w, w.w, s3);
}
#define FD16(w4) { fd4(h0, w4[0], s0, s1, s2, s3);  fd4(h1, w4[1], s0, s1, s2, s3);  \
    fd4(h2, w4[2], s0, s1, s2, s3);  fd4(h3, w4[3], s0, s1, s2, s3);  \
    fd4(h4, w4[4], s0, s1, s2, s3);  fd4(h5, w4[5], s0, s1, s2, s3);  \
    fd4(h6, w4[6], s0, s1, s2, s3);  fd4(h7, w4[7], s0, s1, s2, s3);  \
    fd4(h8, w4[8], s0, s1, s2, s3);  fd4(h9, w4[9], s0, s1, s2, s3);  \
    fd4(h10, w4[10], s0, s1, s2, s3); fd4(h11, w4[11], s0, s1, s2, s3); \
    fd4(h12, w4[12], s0, s1, s2, s3); fd4(h13, w4[13], s0, s1, s2, s3); \
    fd4(h14, w4[14], s0, s1, s2, s3); fd4(h15, w4[15], s0, s1, s2, s3); }

// serial silu-dot over 4 units
__device__ __forceinline__ float accdot(float4 h, float4 w, float act) {
    act = fmaf(silu_f(h.x), w.x, act);
    act = fmaf(silu_f(h.y), w.y, act);
    act = fmaf(silu_f(h.z), w.z, act);
    act = fmaf(silu_f(h.w), w.w, act);
    return act;
}

__global__ void k_copy(const float* __restrict__ src, float* __restrict__ dst, int n4) {
    int i = blockIdx.x * blockDim.x + threadIdx.x;
    if (i < n4) reinterpret_cast<float4*>(dst)[i] = reinterpret_cast<const float4*>(src)[i];
}

// ---- protection net: 4 lanes/node split-hid, full pw1 in LDS, 64 nodes/block ----
__global__ __launch_bounds__(256) void k_protect(
    const float* __restrict__ states, const float* __restrict__ caps,
    const float* __restrict__ pw1, const float* __restrict__ pb1,
    const float* __restrict__ pw2, const float* __restrict__ pb2,
    unsigned* __restrict__ mask, unsigned* __restrict__ mlist,
    unsigned* __restrict__ counters, float* __restrict__ outmask, int N) {
    __shared__ float wl[129 * 64];                // 33 KB: all of pw1 (incl. capacity row)
    unsigned tid = threadIdx.x;
    {   // stage 8256 floats = 2064 float4, coalesced
        const float4* s4 = reinterpret_cast<const float4*>(pw1);
        float4* d4 = reinterpret_cast<float4*>(wl);
#pragma unroll
        for (int q = 0; q < 9; ++q) {
            unsigned idx = tid + q * 256u;
            if (idx < 2064u) d4[idx] = s4[idx];
        }
    }
    __syncthreads();
    unsigned nl = tid >> 2, g = tid & 3u;         // lane g owns hidden units [g*16, g*16+16)
    unsigned n = blockIdx.x * 64u + nl;
    bool active = n < (unsigned)N;
    unsigned nq = active ? n : (unsigned)(N - 1);
    const float4* row = reinterpret_cast<const float4*>(states + (size_t)nq * D);
    float4 a0, a1, a2, a3;
    { const float4* b4 = reinterpret_cast<const float4*>(pb1 + g * 16);
      a0 = b4[0]; a1 = b4[1]; a2 = b4[2]; a3 = b4[3]; }
    const float* wg = wl + g * 16;
#pragma unroll 1
    for (int kb = 0; kb < 32; ++kb) {
        float4 x = row[kb];
        const float* w = wg + (size_t)kb * 4 * HID;
        const float4* w0 = reinterpret_cast<const float4*>(w);
        const float4* w1 = reinterpret_cast<const float4*>(w + HID);
        const float4* w2q = reinterpret_cast<const float4*>(w + 2 * HID);
        const float4* w3q = reinterpret_cast<const float4*>(w + 3 * HID);
        a0 = fma4(x.x, w0[0], a0); a1 = fma4(x.x, w0[1], a1); a2 = fma4(x.x, w0[2], a2); a3 = fma4(x.x, w0[3], a3);
        a0 = fma4(x.y, w1[0], a0); a1 = fma4(x.y, w1[1], a1); a2 = fma4(x.y, w1[2], a2); a3 = fma4(x.y, w1[3], a3);
        a0 = fma4(x.z, w2q[0], a0); a1 = fma4(x.z, w2q[1], a1); a2 = fma4(x.z, w2q[2], a2); a3 = fma4(x.z, w2q[3], a3);
        a0 = fma4(x.w, w3q[0], a0); a1 = fma4(x.w, w3q[1], a1); a2 = fma4(x.w, w3q[2], a2); a3 = fma4(x.w, w3q[3], a3);
    }
    {   // capacity row (input dim 128)
        float xv = caps[nq];
        const float4* wc = reinterpret_cast<const float4*>(wg + (size_t)128 * HID);
        a0 = fma4(xv, wc[0], a0); a1 = fma4(xv, wc[1], a1);
        a2 = fma4(xv, wc[2], a2); a3 = fma4(xv, wc[3], a3);
    }
    // layer-2 partial over this lane's 16 units, then 4-lane butterfly reduce
    const float4* w2 = reinterpret_cast<const float4*>(pw2 + g * 16);
    float p = 0.0f;
    p = accdot(a0, w2[0], p); p = accdot(a1, w2[1], p);
    p = accdot(a2, w2[2], p); p = accdot(a3, w2[3], p);
    p += __shfl_xor(p, 1);
    p += __shfl_xor(p, 2);
    if (active && g == 0) {
        float act = p + pb2[0];
        unsigned m = (act > 0.0f) ? 1u : 0u;
        mask[n] = m;
        outmask[n] = m ? 1.0f : 0.0f;
        if (m) {
            unsigned slot = atomicAdd(&counters[1], 1u);
            mlist[slot] = n;
        }
    }
}

// compact edges with emask = mask[src] && !mask[tgt]
__global__ void k_compact(const int* __restrict__ ei, const unsigned* __restrict__ mask,
                          unsigned* __restrict__ act_eid, unsigned* __restrict__ counters, int E) {
    int e = blockIdx.x * blockDim.x + threadIdx.x;
    if (e >= E) return;
    int s = ei[e], t = ei[E + e];
    if (mask[s] && !mask[t]) {
        unsigned slot = atomicAdd(&counters[0], 1u);
        act_eid[slot] = (unsigned)e;
    }
}

// ---- redistribution MLP: 1 lane/edge, LDS-staged weights, reg-prefetched slabs ----
__global__ __launch_bounds__(256) void k_edge_mlp(
    const float* __restrict__ states, const int* __restrict__ ei,
    const float* __restrict__ rw1, const float* __restrict__ rb1,
    const float* __restrict__ rw2, const float* __restrict__ rb2,
    const float* __restrict__ rw3, const float* __restrict__ rb3,
    const unsigned* __restrict__ act_eid, const unsigned* __restrict__ counters,
    float* __restrict__ rawbuf, unsigned* __restrict__ segmax, int E) {
    __shared__ float wl[4096];                    // 16 KB slab (64 K-rows of rw1)
    __shared__ float w2t[64 * 68];                // rw2 transposed, padded stride
    unsigned cnt = counters[0];
    if (blockIdx.x * 256u >= cnt) return;         // whole block inactive (uniform)
    unsigned tid = threadIdx.x;
    // stage rw2 transposed once (read after the slab loop; barriers order it)
#pragma unroll
    for (int q = 0; q < 16; ++q) {
        int i = (int)tid + q * 256;
        w2t[(i & 63) * 68 + (i >> 6)] = rw2[i];
    }
    unsigned grp = blockIdx.x * 256u + tid;
    bool active = grp < cnt;
    unsigned gq = active ? grp : (cnt - 1);
    int e = (int)act_eid[gq];
    int s = ei[e], tg = ei[E + e];
    const float4* rowA = reinterpret_cast<const float4*>(states + (size_t)s * D);
    const float4* rowB = reinterpret_cast<const float4*>(states + (size_t)tg * D);
    float4 h0, h1, h2, h3, h4, h5, h6, h7, h8, h9, h10, h11, h12, h13, h14, h15;
    INIT16(rb1);
    const float4* src4 = reinterpret_cast<const float4*>(rw1);
    // prologue: prefetch slab 0 into registers
    float4 pf0 = src4[tid], pf1 = src4[tid + 256], pf2 = src4[tid + 512], pf3 = src4[tid + 768];
    for (int sl = 0; sl < 4; ++sl) {
        __syncthreads();                          // wl free (prev compute done)
        {   // commit prefetched slab to LDS
            float4* d4 = reinterpret_cast<float4*>(wl);
            d4[tid] = pf0; d4[tid + 256] = pf1; d4[tid + 512] = pf2; d4[tid + 768] = pf3;
        }
        if (sl < 3) {                             // issue next-slab loads; land during compute
            const float4* nx = src4 + (size_t)(sl + 1) * 1024;
            pf0 = nx[tid]; pf1 = nx[tid + 256]; pf2 = nx[tid + 512]; pf3 = nx[tid + 768];
        }
        __syncthreads();                          // slab visible
        const float4* row = (sl < 2) ? (rowA + sl * 16) : (rowB + (sl - 2) * 16);
#pragma unroll 1
        for (int i = 0; i < 16; ++i) {
            float4 x = row[i];
            const float* w = wl + (size_t)(i * 4) * HID;
            ACC16(x.x, w) ACC16(x.y, w + HID) ACC16(x.z, w + 2 * HID) ACC16(x.w, w + 3 * HID)
        }
    }
    SILU16();
    // layers 2+3 fused: per j, dot(h, rw2T[j]) -> silu -> raw += h2*rw3[j]
    float raw = rb3[0];
#pragma unroll 1
    for (int j = 0; j < HID; ++j) {
        const float4* w4 = reinterpret_cast<const float4*>(w2t + j * 68);
        float s0 = rb2[j], s1 = 0.f, s2 = 0.f, s3 = 0.f;
        FD16(w4);
        float h2v = silu_f((s0 + s1) + (s2 + s3));
        raw = fmaf(h2v, rw3[j], raw);
    }
    if (active) {
        rawbuf[grp] = raw;
        atomicMax(&segmax[s], fenc(raw));
    }
}

__global__ void k_exp(const int* __restrict__ ei, const unsigned* __restrict__ act_eid,
                      const unsigned* __restrict__ counters, const unsigned* __restrict__ segmax,
                      float* __restrict__ rawbuf, float* __restrict__ denom, int E) {
    unsigned t = blockIdx.x * blockDim.x + threadIdx.x;
    if (t >= counters[0]) return;
    int e = (int)act_eid[t];
    int s = ei[e];
    float ev = expf(rawbuf[t] - fdec(segmax[s]));
    rawbuf[t] = ev;
    atomicAdd(&denom[s], ev);
}

// wave-per-active-edge: out[tgt] += w * states[src]
__global__ __launch_bounds__(256) void k_scatter(
    const float* __restrict__ states, const int* __restrict__ ei,
    const unsigned* __restrict__ act_eid, const unsigned* __restrict__ counters,
    const float* __restrict__ rawbuf, const float* __restrict__ denom,
    float* __restrict__ out, int E) {
    unsigned w = blockIdx.x * (blockDim.x >> 6) + (threadIdx.x >> 6);
    unsigned lane = threadIdx.x & 63u;
    if (w >= counters[0]) return;
    int e = (int)act_eid[w];
    int s = ei[e], tg = ei[E + e];
    float wt = rawbuf[w] / denom[s];
    const float* srow = states + (size_t)s * D;
    float* orow = out + (size_t)tg * D;
    atomicAdd(&orow[lane], wt * srow[lane]);
    atomicAdd(&orow[lane + 64], wt * srow[lane + 64]);
}

// failed nodes: out = tanh(redist @ tw + tb) * 0.05
// 8 nodes per 256-thread block; tw element reused 4x per thread
__global__ __launch_bounds__(256) void k_jump(
    const float* __restrict__ tw, const float* __restrict__ tb,
    const unsigned* __restrict__ mlist, const unsigned* __restrict__ counters,
    float* __restrict__ out) {
    __shared__ float xs[8][D];
    unsigned cnt = counters[1];
    unsigned base = blockIdx.x * 8u;
    if (base >= cnt || cnt == 0) return;          // uniform
    unsigned tid = threadIdx.x;
    unsigned d = tid & 127u, r = tid >> 7;        // r in {0,1}
    {   // stage 8 rows (clamped): 32 threads per row, float4 each
        unsigned j = tid >> 5;
        unsigned c = (tid & 31u) * 4u;
        unsigned slot = base + j; if (slot >= cnt) slot = cnt - 1;
        int nn = (int)mlist[slot];
        *reinterpret_cast<float4*>(&xs[j][c]) =
            *reinterpret_cast<const float4*>(&out[(size_t)nn * D + c]);
    }
    __syncthreads();
    float tbd = tb[d];
    float a0 = tbd, a1 = tbd, a2 = tbd, a3 = tbd;
    const float* x0 = &xs[r * 4 + 0][0];
    const float* x1 = &xs[r * 4 + 1][0];
    const float* x2 = &xs[r * 4 + 2][0];
    const float* x3 = &xs[r * 4 + 3][0];
#pragma unroll 1
    for (int k = 0; k < D; ++k) {
        float w = tw[(size_t)k * D + d];
        a0 = fmaf(x0[k], w, a0);
        a1 = fmaf(x1[k], w, a1);
        a2 = fmaf(x2[k], w, a2);
        a3 = fmaf(x3[k], w, a3);
    }
    float res[4] = {a0, a1, a2, a3};
#pragma unroll
    for (int j2 = 0; j2 < 4; ++j2) {
        unsigned slot = base + r * 4 + j2;
        if (slot < cnt) {
            int nn = (int)mlist[slot];
            out[(size_t)nn * D + d] = tanhf(res[j2]) * 0.05f;
        }
    }
}

extern "C" void kernel_launch(void* const* d_in, const int* in_sizes, int n_in,
                              void* d_out, int out_size, void* d_ws, size_t ws_size,
                              hipStream_t stream) {
    const float* states = (const float*)d_in[0];
    const float* caps   = (const float*)d_in[1];
    const int*   ei     = (const int*)d_in[2];
    const float* rw1 = (const float*)d_in[3];  const float* rb1 = (const float*)d_in[4];
    const float* rw2 = (const float*)d_in[5];  const float* rb2 = (const float*)d_in[6];
    const float* rw3 = (const float*)d_in[7];  const float* rb3 = (const float*)d_in[8];
    const float* pw1 = (const float*)d_in[9];  const float* pb1 = (const float*)d_in[10];
    const float* pw2 = (const float*)d_in[11]; const float* pb2 = (const float*)d_in[12];
    const float* tw  = (const float*)d_in[13]; const float* tb  = (const float*)d_in[14];
    const int N = in_sizes[1];
    const int E = in_sizes[2] / 2;
    float* out = (float*)d_out;

    // ws layout (u32 units): [0..3] counters | segmax N | denom N | mask N | mlist N | act_eid E | rawbuf E
    unsigned* ws       = (unsigned*)d_ws;
    unsigned* counters = ws;
    unsigned* segmax   = ws + 4;
    float*    denom    = (float*)(ws + 4 + (size_t)N);
    unsigned* mask     = ws + 4 + 2 * (size_t)N;
    unsigned* mlist    = ws + 4 + 3 * (size_t)N;
    unsigned* act_eid  = ws + 4 + 4 * (size_t)N;
    float*    rawbuf   = (float*)(ws + 4 + 4 * (size_t)N + (size_t)E);

    hipMemsetAsync(d_ws, 0, (size_t)(4 + 2 * (size_t)N) * 4, stream);

    const int n4 = N * D / 4;
    k_copy<<<(n4 + 255) / 256, 256, 0, stream>>>(states, out, n4);
    k_protect<<<(N + 63) / 64, 256, 0, stream>>>(states, caps, pw1, pb1, pw2, pb2,
                                                 mask, mlist, counters, out + (size_t)N * D, N);
    k_compact<<<(E + 255) / 256, 256, 0, stream>>>(ei, mask, act_eid, counters, E);
    k_edge_mlp<<<(E + 255) / 256, 256, 0, stream>>>(states, ei, rw1, rb1, rw2, rb2, rw3, rb3,
                                                    act_eid, counters, rawbuf, segmax, E);
    k_exp<<<(E + 255) / 256, 256, 0, stream>>>(ei, act_eid, counters, segmax, rawbuf, denom, E);
    k_scatter<<<(E + 3) / 4, 256, 0, stream>>>(states, ei, act_eid, counters, rawbuf, denom, out, E);
    k_jump<<<(N + 7) / 8, 256, 0, stream>>>(tw, tb, mlist, counters, out);
}